// Round 15
// baseline (154.687 us; speedup 1.0000x reference)
//
#include <hip/hip_runtime.h>
#include <hip/hip_bf16.h>

#define N_NODES 8192
#define F_IN    512
#define H_DIM   256
#define O_DIM   128
#define C_DIM   64
#define E_EDGES 262144
#define BCAP    96

typedef __attribute__((ext_vector_type(8))) short bf16x8;
typedef __attribute__((ext_vector_type(8))) _Float16 f16x8;
typedef __attribute__((ext_vector_type(4))) float f32x4;

__device__ inline unsigned short f2bf(float v) {
    __hip_bfloat16 h = __float2bfloat16(v);
    return *reinterpret_cast<unsigned short*>(&h);
}
__device__ inline float bf2f(unsigned short u) {
    return __uint_as_float((unsigned)u << 16);
}
__device__ inline float4 bf4_to_f4(ushort4 u) {
    float4 f;
    f.x = bf2f(u.x); f.y = bf2f(u.y); f.z = bf2f(u.z); f.w = bf2f(u.w);
    return f;
}
__device__ inline bf16x8 pack_bf8(float4 a, float4 b) {
    bf16x8 r;
    r[0] = (short)f2bf(a.x); r[1] = (short)f2bf(a.y);
    r[2] = (short)f2bf(a.z); r[3] = (short)f2bf(a.w);
    r[4] = (short)f2bf(b.x); r[5] = (short)f2bf(b.y);
    r[6] = (short)f2bf(b.z); r[7] = (short)f2bf(b.w);
    return r;
}

// ---------------- K1: prep — zero cnt; W1 -> W1^T bf16; W2 -> W2^T bf16 ----------------
__global__ __launch_bounds__(256) void prep_kernel(
    const float* __restrict__ W1, unsigned short* __restrict__ w1t,
    const float* __restrict__ W2, unsigned short* __restrict__ w2t,
    int* __restrict__ cnt)
{
    const int NW1 = F_IN * H_DIM;             // 131072
    const int NW2 = H_DIM * O_DIM;            // 32768
    int idx = blockIdx.x * 256 + threadIdx.x;
    if (idx < N_NODES) cnt[idx] = 0;
    if (idx < NW1) {
        int k = idx / H_DIM, n = idx % H_DIM;
        w1t[n * F_IN + k] = f2bf(W1[idx]);
    } else if (idx < NW1 + NW2) {
        int j = idx - NW1;
        int k = j / O_DIM, n = j % O_DIM;
        w2t[n * H_DIM + k] = f2bf(W2[j]);
    }
}

// ---------------- K2: gemm1 — edge bucket-fill + raw1 = bf16(bf16(x) @ w1t^T) ----------------
// Block tile 32x64 (4 waves 2x2, wave tile 16x32). grid (4, 256) = 1024 blocks = 4/CU.
__global__ __launch_bounds__(256) void gemm1_kernel(
    const float* __restrict__ x,
    const unsigned short* __restrict__ Bt,
    const int* __restrict__ srcv, const int* __restrict__ dstv,
    int* __restrict__ cnt, int* __restrict__ slots,
    unsigned short* __restrict__ out)   // raw1 [N_NODES][H_DIM]
{
    // edge fill: exactly 1 edge per thread (1024 blocks * 256 thr = 262144)
    {
        int e0 = (blockIdx.y * gridDim.x + blockIdx.x) * 256 + threadIdx.x;
        int d = dstv[e0];
        int pos = atomicAdd(&cnt[d], 1);
        slots[d * BCAP + pos] = srcv[e0];
    }

    constexpr int N = H_DIM, K = F_IN, MW = 1, NW = 2;
    const int tid = threadIdx.x;
    const int lane = tid & 63;
    const int wid = tid >> 6;
    const int r = lane & 15;
    const int kg = lane >> 4;
    const int m0 = blockIdx.y * (2 * MW * 16) + (wid >> 1) * (MW * 16);
    const int n0 = blockIdx.x * (2 * NW * 16) + (wid & 1) * (NW * 16);

    f32x4 acc[MW][NW];
#pragma unroll
    for (int mi = 0; mi < MW; ++mi)
#pragma unroll
        for (int ni = 0; ni < NW; ++ni) acc[mi][ni] = (f32x4){0.f, 0.f, 0.f, 0.f};

    for (int k0 = 0; k0 < K; k0 += 32) {
        const int kof = k0 + kg * 8;
        bf16x8 a[MW], b[NW];
#pragma unroll
        for (int mi = 0; mi < MW; ++mi) {
            const float* xr = x + (size_t)(m0 + mi * 16 + r) * K + kof;
            float4 f0 = *(const float4*)xr;
            float4 f1 = *(const float4*)(xr + 4);
            a[mi] = pack_bf8(f0, f1);
        }
#pragma unroll
        for (int ni = 0; ni < NW; ++ni)
            b[ni] = *(const bf16x8*)(Bt + (size_t)(n0 + ni * 16 + r) * K + kof);
#pragma unroll
        for (int mi = 0; mi < MW; ++mi)
#pragma unroll
            for (int ni = 0; ni < NW; ++ni)
                acc[mi][ni] = __builtin_amdgcn_mfma_f32_16x16x32_bf16(a[mi], b[ni], acc[mi][ni], 0, 0, 0);
    }

#pragma unroll
    for (int mi = 0; mi < MW; ++mi) {
        int rowb = m0 + mi * 16 + kg * 4;
#pragma unroll
        for (int ni = 0; ni < NW; ++ni) {
            int col = n0 + ni * 16 + r;
#pragma unroll
            for (int i = 0; i < 4; ++i)
                out[(size_t)(rowb + i) * N + col] = f2bf(acc[mi][ni][i]);
        }
    }
}

// ---------------- K3: fused gather1 + gemm2 (512 threads, 8 waves) ----------------
__global__ __launch_bounds__(512) void gather_gemm2_kernel(
    const unsigned short* __restrict__ raw,   // raw1 [8192][256] bf16, unscaled
    const int* __restrict__ cnt, const int* __restrict__ slots,
    const float* __restrict__ b1,
    const unsigned short* __restrict__ w2t,
    unsigned short* __restrict__ g2b)         // [8192][128] bf16, dinv-scaled
{
    __shared__ unsigned short hs[16 * 256];   // 8 KB, row stride 512 B, XOR-swizzled 16B slots
    const int tid = threadIdx.x;
    const int wid = tid >> 6;                 // 0..7
    const int lane = tid & 63;
    const int nb = blockIdx.x * 16;
    const ushort4* G4 = (const ushort4*)raw;

    // ---- phase 1: each wave gathers 2 node rows ----
    for (int q = 0; q < 2; ++q) {
        const int ln = wid * 2 + q;
        const int node = nb + ln;
        const int deg = cnt[node];
        const int* sl = slots + node * BCAP;
        const float di = rsqrtf((float)deg + 1.0f);

        float4 selfv = bf4_to_f4(G4[(size_t)node * 64 + lane]);
        float4 acc, acc2;
        acc.x = di * selfv.x; acc.y = di * selfv.y;
        acc.z = di * selfv.z; acc.w = di * selfv.w;
        acc2 = make_float4(0.f, 0.f, 0.f, 0.f);

        int e = 0;
        for (; e + 8 <= deg; e += 8) {
            int s[8];
            ushort4 u[8];
            float d[8];
#pragma unroll
            for (int j = 0; j < 8; ++j) s[j] = sl[e + j];
#pragma unroll
            for (int j = 0; j < 8; ++j) u[j] = G4[(size_t)s[j] * 64 + lane];
#pragma unroll
            for (int j = 0; j < 8; ++j) d[j] = rsqrtf((float)cnt[s[j]] + 1.0f);
#pragma unroll
            for (int j = 0; j < 8; j += 2) {
                float4 v0 = bf4_to_f4(u[j]);
                float4 v1 = bf4_to_f4(u[j + 1]);
                acc.x = fmaf(d[j], v0.x, acc.x);     acc.y = fmaf(d[j], v0.y, acc.y);
                acc.z = fmaf(d[j], v0.z, acc.z);     acc.w = fmaf(d[j], v0.w, acc.w);
                acc2.x = fmaf(d[j+1], v1.x, acc2.x); acc2.y = fmaf(d[j+1], v1.y, acc2.y);
                acc2.z = fmaf(d[j+1], v1.z, acc2.z); acc2.w = fmaf(d[j+1], v1.w, acc2.w);
            }
        }
        for (; e < deg; ++e) {
            int s0 = sl[e];
            float d0 = rsqrtf((float)cnt[s0] + 1.0f);
            float4 v0 = bf4_to_f4(G4[(size_t)s0 * 64 + lane]);
            acc.x = fmaf(d0, v0.x, acc.x); acc.y = fmaf(d0, v0.y, acc.y);
            acc.z = fmaf(d0, v0.z, acc.z); acc.w = fmaf(d0, v0.w, acc.w);
        }
        acc.x += acc2.x; acc.y += acc2.y; acc.z += acc2.z; acc.w += acc2.w;

        const float4 bv = ((const float4*)b1)[lane];
        float4 rr;
        rr.x = di * acc.x + bv.x;
        rr.y = di * acc.y + bv.y;
        rr.z = di * acc.z + bv.z;
        rr.w = di * acc.w + bv.w;
        rr.x = rr.x > 0.f ? rr.x : 0.f;
        rr.y = rr.y > 0.f ? rr.y : 0.f;
        rr.z = rr.z > 0.f ? rr.z : 0.f;
        rr.w = rr.w > 0.f ? rr.w : 0.f;

        ushort4 hv;
        hv.x = f2bf(rr.x); hv.y = f2bf(rr.y); hv.z = f2bf(rr.z); hv.w = f2bf(rr.w);
        int s0 = (lane >> 1) ^ (ln & 7);
        *(ushort4*)((char*)hs + ln * 512 + (s0 << 4) + (lane & 1) * 8) = hv;
    }
    __syncthreads();

    // ---- phase 2: 16x256 @ W2^T(128x256) -> 16x128; wave wid covers cols wid*16..+15 ----
    const int r = lane & 15;
    const int kg = lane >> 4;
    const int wn = wid * 16;

    f32x4 acc = (f32x4){0.f, 0.f, 0.f, 0.f};
    for (int k0 = 0; k0 < H_DIM; k0 += 32) {
        int slot = ((k0 >> 3) + kg) ^ (r & 7);
        bf16x8 a = *(const bf16x8*)((const char*)hs + r * 512 + (slot << 4));
        bf16x8 b = *(const bf16x8*)(w2t + (size_t)(wn + r) * H_DIM + k0 + kg * 8);
        acc = __builtin_amdgcn_mfma_f32_16x16x32_bf16(a, b, acc, 0, 0, 0);
    }

#pragma unroll
    for (int i = 0; i < 4; ++i) {
        int row = nb + kg * 4 + i;
        float di = rsqrtf((float)cnt[row] + 1.0f);
        g2b[(size_t)row * O_DIM + wn + r] = f2bf(di * acc[i]);
    }
}

// ---------------- K4: fused gather layer 2 + head — 2 nodes per 256-thr block ----------------
__global__ __launch_bounds__(256) void gather_head_kernel(
    const unsigned short* __restrict__ g2,   // [8192][128] bf16, dinv-scaled
    const int* __restrict__ cnt, const int* __restrict__ slots,
    const float* __restrict__ b2,
    const float* __restrict__ Wmu, const float* __restrict__ bmu,
    const float* __restrict__ Wlv, const float* __restrict__ blv,
    const float* __restrict__ eps,
    float* __restrict__ mu_out, float* __restrict__ lv_out,
    _Float16* __restrict__ zr)
{
    __shared__ float zsw[2][2][O_DIM];
    __shared__ float zs[2][O_DIM];
    __shared__ float mu_s[2][C_DIM];
    __shared__ float lv_s[2][C_DIM];
    const int t = threadIdx.x;
    const int nl = t >> 7;                 // node-local 0/1
    const int tl = t & 127;
    const int node = blockIdx.x * 2 + nl;
    const int w = tl >> 6;
    const int lane = tl & 63;

    const int deg = cnt[node];
    const int* sl = slots + node * BCAP;
    const unsigned int* G2 = (const unsigned int*)g2;  // row stride 64 uints (128 bf16)

    float a0 = 0.f, a1 = 0.f, c0 = 0.f, c1 = 0.f;
    if (w == 0) {
        unsigned int u = G2[(size_t)node * 64 + lane];
        a0 = bf2f((unsigned short)u);
        a1 = bf2f((unsigned short)(u >> 16));
    }
    int e = w;
    for (; e + 6 < deg; e += 8) {
        unsigned int u0 = G2[(size_t)sl[e]     * 64 + lane];
        unsigned int u1 = G2[(size_t)sl[e + 2] * 64 + lane];
        unsigned int u2 = G2[(size_t)sl[e + 4] * 64 + lane];
        unsigned int u3 = G2[(size_t)sl[e + 6] * 64 + lane];
        a0 += bf2f((unsigned short)u0) + bf2f((unsigned short)u1);
        a1 += bf2f((unsigned short)(u0 >> 16)) + bf2f((unsigned short)(u1 >> 16));
        c0 += bf2f((unsigned short)u2) + bf2f((unsigned short)u3);
        c1 += bf2f((unsigned short)(u2 >> 16)) + bf2f((unsigned short)(u3 >> 16));
    }
    for (; e < deg; e += 2) {
        unsigned int u = G2[(size_t)sl[e] * 64 + lane];
        a0 += bf2f((unsigned short)u);
        a1 += bf2f((unsigned short)(u >> 16));
    }
    zsw[nl][w][2 * lane]     = a0 + c0;
    zsw[nl][w][2 * lane + 1] = a1 + c1;
    __syncthreads();

    float dv = rsqrtf((float)deg + 1.0f);
    zs[nl][tl] = dv * (zsw[nl][0][tl] + zsw[nl][1][tl]) + b2[tl];
    __syncthreads();

    const int c = tl & 63;
    const float* W = (tl < 64) ? Wmu : Wlv;
    float s = 0.f;
#pragma unroll 8
    for (int k = 0; k < O_DIM; ++k) s += zs[nl][k] * W[k * C_DIM + c];
    if (tl < 64) {
        s += bmu[c];
        mu_out[(size_t)node * C_DIM + c] = s;
        mu_s[nl][c] = s;
    } else {
        s += blv[c];
        lv_out[(size_t)node * C_DIM + c] = s;
        lv_s[nl][c] = s;
    }
    __syncthreads();
    if (tl < 64) {
        float stdv = __expf(0.5f * lv_s[nl][c]);
        float v = mu_s[nl][c] + eps[(size_t)node * C_DIM + c] * stdv;
        zr[(size_t)node * C_DIM + c] = (_Float16)v;
    }
}

// ---------------- K5: adj = sigmoid(zr @ zr^T), fp16 MFMA, LDS-staged coalesced NT stores ----------------
__global__ __launch_bounds__(256) void adj_mfma_kernel(
    const _Float16* __restrict__ Z, float* __restrict__ out)
{
    __shared__ float ls[128 * 128];   // 64 KB; float4-slot XOR-swizzled by row&7
    const int tid = threadIdx.x;
    const int lane = tid & 63;
    const int wid = tid >> 6;
    const int r = lane & 15;
    const int kg = lane >> 4;
    const int mb = blockIdx.y * 128;
    const int nb = blockIdx.x * 128;
    const int m0 = (wid >> 1) * 64;
    const int n0 = (wid & 1) * 64;

    f16x8 a[4][2], b[4][2];
#pragma unroll
    for (int mi = 0; mi < 4; ++mi)
#pragma unroll
        for (int ks = 0; ks < 2; ++ks) {
            a[mi][ks] = *(const f16x8*)(Z + (size_t)(mb + m0 + mi * 16 + r) * C_DIM + ks * 32 + kg * 8);
            b[mi][ks] = *(const f16x8*)(Z + (size_t)(nb + n0 + mi * 16 + r) * C_DIM + ks * 32 + kg * 8);
        }

    f32x4 acc[4][4];
#pragma unroll
    for (int mi = 0; mi < 4; ++mi)
#pragma unroll
        for (int ni = 0; ni < 4; ++ni) acc[mi][ni] = (f32x4){0.f, 0.f, 0.f, 0.f};

#pragma unroll
    for (int mi = 0; mi < 4; ++mi)
#pragma unroll
        for (int ni = 0; ni < 4; ++ni) {
            acc[mi][ni] = __builtin_amdgcn_mfma_f32_16x16x32_f16(a[mi][0], b[ni][0], acc[mi][ni], 0, 0, 0);
            acc[mi][ni] = __builtin_amdgcn_mfma_f32_16x16x32_f16(a[mi][1], b[ni][1], acc[mi][ni], 0, 0, 0);
        }

    // sigmoid -> LDS (swizzled float4 slots)
#pragma unroll
    for (int mi = 0; mi < 4; ++mi) {
        int lr_b = m0 + mi * 16 + kg * 4;
#pragma unroll
        for (int ni = 0; ni < 4; ++ni) {
            int lc = n0 + ni * 16 + r;
#pragma unroll
            for (int i = 0; i < 4; ++i) {
                float v = acc[mi][ni][i];
                float e = __expf(-v);
                float sg = __builtin_amdgcn_rcpf(1.0f + e);
                int lr = lr_b + i;
                ls[lr * 128 + (((lc >> 2) ^ (lr & 7)) << 2) + (lc & 3)] = sg;
            }
        }
    }
    __syncthreads();

    // coalesced NT stores: 512B contiguous per wave-instruction
#pragma unroll
    for (int j = 0; j < 16; ++j) {
        int idx = j * 256 + tid;
        int row = idx >> 5;
        int s = idx & 31;
        f32x4 v = *(const f32x4*)&ls[row * 128 + (((s ^ (row & 7)) & 31) << 2)];
        __builtin_nontemporal_store(v, (f32x4*)&out[(size_t)(mb + row) * N_NODES + nb + s * 4]);
    }
}

extern "C" void kernel_launch(void* const* d_in, const int* in_sizes, int n_in,
                              void* d_out, int out_size, void* d_ws, size_t ws_size,
                              hipStream_t stream) {
    const float* x   = (const float*)d_in[0];
    const int*   ei  = (const int*)  d_in[1];
    const float* eps = (const float*)d_in[2];
    const float* W1  = (const float*)d_in[3];
    const float* b1  = (const float*)d_in[4];
    const float* W2  = (const float*)d_in[5];
    const float* b2  = (const float*)d_in[6];
    const float* Wmu = (const float*)d_in[7];
    const float* bmu = (const float*)d_in[8];
    const float* Wlv = (const float*)d_in[9];
    const float* blv = (const float*)d_in[10];
    float* out = (float*)d_out;

    const int* srcv = ei;
    const int* dstv = ei + E_EDGES;

    char* p = (char*)d_ws;
    auto carve = [&](size_t bytes) -> void* {
        void* q = (void*)p;
        p += (bytes + 255) & ~(size_t)255;
        return q;
    };
    int* cnt      = (int*)carve(N_NODES * 4);
    int* slots    = (int*)carve((size_t)N_NODES * BCAP * 4);
    unsigned short* w1t  = (unsigned short*)carve((size_t)F_IN * H_DIM * 2);
    unsigned short* w2t  = (unsigned short*)carve((size_t)H_DIM * O_DIM * 2);
    unsigned short* raw1 = (unsigned short*)carve((size_t)N_NODES * H_DIM * 2);
    unsigned short* g2b  = (unsigned short*)carve((size_t)N_NODES * O_DIM * 2);
    _Float16* zr         = (_Float16*)carve((size_t)N_NODES * C_DIM * 2);

    float* mu_out = out + (size_t)N_NODES * N_NODES;
    float* lv_out = mu_out + (size_t)N_NODES * C_DIM;

    // ---- 1. prep: cnt zero + W1^T bf16 + W2^T bf16 ----
    {
        const int total = F_IN * H_DIM + H_DIM * O_DIM;  // 163840
        prep_kernel<<<(total + 255) / 256, 256, 0, stream>>>(
            W1, w1t, W2, w2t, cnt);
    }

    // ---- 2. gemm1: edge bucket-fill + raw1 = bf16(x)@w1t^T, 32x64 tiles, 1024 blocks ----
    {
        dim3 grid(H_DIM / 64, N_NODES / 32);   // 4 x 256 = 1024 blocks
        gemm1_kernel<<<grid, 256, 0, stream>>>(
            x, w1t, srcv, dstv, cnt, slots, raw1);
    }

    // ---- 3. fused gather1 + gemm2 -> g2b ----
    gather_gemm2_kernel<<<N_NODES / 16, 512, 0, stream>>>(
        raw1, cnt, slots, b1, w2t, g2b);

    // ---- 4. fused gather 2 + head (zr fp16), 2 nodes/block ----
    gather_head_kernel<<<N_NODES / 2, 256, 0, stream>>>(
        g2b, cnt, slots, b2, Wmu, bmu, Wlv, blv, eps,
        mu_out, lv_out, zr);

    // ---- 5. adjacency reconstruction (LDS-staged coalesced NT stores) ----
    {
        dim3 grid(N_NODES / 128, N_NODES / 128);
        adj_mfma_kernel<<<grid, 256, 0, stream>>>(zr, out);
    }
}

// Round 16
// 146.886 us; speedup vs baseline: 1.0531x; 1.0531x over previous
//
#include <hip/hip_runtime.h>
#include <hip/hip_bf16.h>

#define N_NODES 8192
#define F_IN    512
#define H_DIM   256
#define O_DIM   128
#define C_DIM   64
#define E_EDGES 262144
#define BCAP    96

typedef __attribute__((ext_vector_type(8))) short bf16x8;
typedef __attribute__((ext_vector_type(8))) _Float16 f16x8;
typedef __attribute__((ext_vector_type(4))) float f32x4;

__device__ inline unsigned short f2bf(float v) {
    __hip_bfloat16 h = __float2bfloat16(v);
    return *reinterpret_cast<unsigned short*>(&h);
}
__device__ inline float bf2f(unsigned short u) {
    return __uint_as_float((unsigned)u << 16);
}
__device__ inline float4 bf4_to_f4(ushort4 u) {
    float4 f;
    f.x = bf2f(u.x); f.y = bf2f(u.y); f.z = bf2f(u.z); f.w = bf2f(u.w);
    return f;
}
__device__ inline bf16x8 pack_bf8(float4 a, float4 b) {
    bf16x8 r;
    r[0] = (short)f2bf(a.x); r[1] = (short)f2bf(a.y);
    r[2] = (short)f2bf(a.z); r[3] = (short)f2bf(a.w);
    r[4] = (short)f2bf(b.x); r[5] = (short)f2bf(b.y);
    r[6] = (short)f2bf(b.z); r[7] = (short)f2bf(b.w);
    return r;
}

// ---------------- K1: prep — zero cnt; W1 -> W1^T bf16; W2 -> W2^T bf16 ----------------
__global__ __launch_bounds__(256) void prep_kernel(
    const float* __restrict__ W1, unsigned short* __restrict__ w1t,
    const float* __restrict__ W2, unsigned short* __restrict__ w2t,
    int* __restrict__ cnt)
{
    const int NW1 = F_IN * H_DIM;             // 131072
    const int NW2 = H_DIM * O_DIM;            // 32768
    int idx = blockIdx.x * 256 + threadIdx.x;
    if (idx < N_NODES) cnt[idx] = 0;
    if (idx < NW1) {
        int k = idx / H_DIM, n = idx % H_DIM;
        w1t[n * F_IN + k] = f2bf(W1[idx]);
    } else if (idx < NW1 + NW2) {
        int j = idx - NW1;
        int k = j / O_DIM, n = j % O_DIM;
        w2t[n * H_DIM + k] = f2bf(W2[j]);
    }
}

// ---------------- K2: gemm1 — edge bucket-fill + raw1 = bf16(bf16(x) @ w1t^T) ----------------
// 64x64 tiles (4 waves 2x2, wave tile 32x32). grid (4, 128) = 512 blocks.
__global__ __launch_bounds__(256) void gemm1_kernel(
    const float* __restrict__ x,
    const unsigned short* __restrict__ Bt,
    const int* __restrict__ srcv, const int* __restrict__ dstv,
    int* __restrict__ cnt, int* __restrict__ slots,
    unsigned short* __restrict__ out)   // raw1 [N_NODES][H_DIM]
{
    // edge fill: exactly 2 edges per thread (512 blocks * 256 thr * 2 = 262144)
    {
        int flat = (blockIdx.y * gridDim.x + blockIdx.x) * 256 + threadIdx.x;
        int e0 = flat * 2;
#pragma unroll
        for (int j = 0; j < 2; ++j) {
            int d = dstv[e0 + j];
            int pos = atomicAdd(&cnt[d], 1);
            slots[d * BCAP + pos] = srcv[e0 + j];
        }
    }

    constexpr int N = H_DIM, K = F_IN, MW = 2, NW = 2;
    const int tid = threadIdx.x;
    const int lane = tid & 63;
    const int wid = tid >> 6;
    const int r = lane & 15;
    const int kg = lane >> 4;
    const int m0 = blockIdx.y * (2 * MW * 16) + (wid >> 1) * (MW * 16);
    const int n0 = blockIdx.x * (2 * NW * 16) + (wid & 1) * (NW * 16);

    f32x4 acc[MW][NW];
#pragma unroll
    for (int mi = 0; mi < MW; ++mi)
#pragma unroll
        for (int ni = 0; ni < NW; ++ni) acc[mi][ni] = (f32x4){0.f, 0.f, 0.f, 0.f};

    for (int k0 = 0; k0 < K; k0 += 32) {
        const int kof = k0 + kg * 8;
        bf16x8 a[MW], b[NW];
#pragma unroll
        for (int mi = 0; mi < MW; ++mi) {
            const float* xr = x + (size_t)(m0 + mi * 16 + r) * K + kof;
            float4 f0 = *(const float4*)xr;
            float4 f1 = *(const float4*)(xr + 4);
            a[mi] = pack_bf8(f0, f1);
        }
#pragma unroll
        for (int ni = 0; ni < NW; ++ni)
            b[ni] = *(const bf16x8*)(Bt + (size_t)(n0 + ni * 16 + r) * K + kof);
#pragma unroll
        for (int mi = 0; mi < MW; ++mi)
#pragma unroll
            for (int ni = 0; ni < NW; ++ni)
                acc[mi][ni] = __builtin_amdgcn_mfma_f32_16x16x32_bf16(a[mi], b[ni], acc[mi][ni], 0, 0, 0);
    }

#pragma unroll
    for (int mi = 0; mi < MW; ++mi) {
        int rowb = m0 + mi * 16 + kg * 4;
#pragma unroll
        for (int ni = 0; ni < NW; ++ni) {
            int col = n0 + ni * 16 + r;
#pragma unroll
            for (int i = 0; i < 4; ++i)
                out[(size_t)(rowb + i) * N + col] = f2bf(acc[mi][ni][i]);
        }
    }
}

// ---------------- K3: fused gather1 + gemm2 (512 threads, 8 waves) ----------------
__global__ __launch_bounds__(512) void gather_gemm2_kernel(
    const unsigned short* __restrict__ raw,   // raw1 [8192][256] bf16, unscaled
    const int* __restrict__ cnt, const int* __restrict__ slots,
    const float* __restrict__ b1,
    const unsigned short* __restrict__ w2t,
    unsigned short* __restrict__ g2b)         // [8192][128] bf16, dinv-scaled
{
    __shared__ unsigned short hs[16 * 256];   // 8 KB, row stride 512 B, XOR-swizzled 16B slots
    const int tid = threadIdx.x;
    const int wid = tid >> 6;                 // 0..7
    const int lane = tid & 63;
    const int nb = blockIdx.x * 16;
    const ushort4* G4 = (const ushort4*)raw;

    // ---- phase 1: each wave gathers 2 node rows ----
    for (int q = 0; q < 2; ++q) {
        const int ln = wid * 2 + q;
        const int node = nb + ln;
        const int deg = cnt[node];
        const int* sl = slots + node * BCAP;
        const float di = rsqrtf((float)deg + 1.0f);

        float4 selfv = bf4_to_f4(G4[(size_t)node * 64 + lane]);
        float4 acc, acc2;
        acc.x = di * selfv.x; acc.y = di * selfv.y;
        acc.z = di * selfv.z; acc.w = di * selfv.w;
        acc2 = make_float4(0.f, 0.f, 0.f, 0.f);

        int e = 0;
        for (; e + 8 <= deg; e += 8) {
            int s[8];
            ushort4 u[8];
            float d[8];
#pragma unroll
            for (int j = 0; j < 8; ++j) s[j] = sl[e + j];
#pragma unroll
            for (int j = 0; j < 8; ++j) u[j] = G4[(size_t)s[j] * 64 + lane];
#pragma unroll
            for (int j = 0; j < 8; ++j) d[j] = rsqrtf((float)cnt[s[j]] + 1.0f);
#pragma unroll
            for (int j = 0; j < 8; j += 2) {
                float4 v0 = bf4_to_f4(u[j]);
                float4 v1 = bf4_to_f4(u[j + 1]);
                acc.x = fmaf(d[j], v0.x, acc.x);     acc.y = fmaf(d[j], v0.y, acc.y);
                acc.z = fmaf(d[j], v0.z, acc.z);     acc.w = fmaf(d[j], v0.w, acc.w);
                acc2.x = fmaf(d[j+1], v1.x, acc2.x); acc2.y = fmaf(d[j+1], v1.y, acc2.y);
                acc2.z = fmaf(d[j+1], v1.z, acc2.z); acc2.w = fmaf(d[j+1], v1.w, acc2.w);
            }
        }
        for (; e < deg; ++e) {
            int s0 = sl[e];
            float d0 = rsqrtf((float)cnt[s0] + 1.0f);
            float4 v0 = bf4_to_f4(G4[(size_t)s0 * 64 + lane]);
            acc.x = fmaf(d0, v0.x, acc.x); acc.y = fmaf(d0, v0.y, acc.y);
            acc.z = fmaf(d0, v0.z, acc.z); acc.w = fmaf(d0, v0.w, acc.w);
        }
        acc.x += acc2.x; acc.y += acc2.y; acc.z += acc2.z; acc.w += acc2.w;

        const float4 bv = ((const float4*)b1)[lane];
        float4 rr;
        rr.x = di * acc.x + bv.x;
        rr.y = di * acc.y + bv.y;
        rr.z = di * acc.z + bv.z;
        rr.w = di * acc.w + bv.w;
        rr.x = rr.x > 0.f ? rr.x : 0.f;
        rr.y = rr.y > 0.f ? rr.y : 0.f;
        rr.z = rr.z > 0.f ? rr.z : 0.f;
        rr.w = rr.w > 0.f ? rr.w : 0.f;

        ushort4 hv;
        hv.x = f2bf(rr.x); hv.y = f2bf(rr.y); hv.z = f2bf(rr.z); hv.w = f2bf(rr.w);
        int s0 = (lane >> 1) ^ (ln & 7);
        *(ushort4*)((char*)hs + ln * 512 + (s0 << 4) + (lane & 1) * 8) = hv;
    }
    __syncthreads();

    // ---- phase 2: 16x256 @ W2^T(128x256) -> 16x128; wave wid covers cols wid*16..+15 ----
    const int r = lane & 15;
    const int kg = lane >> 4;
    const int wn = wid * 16;

    f32x4 acc = (f32x4){0.f, 0.f, 0.f, 0.f};
    for (int k0 = 0; k0 < H_DIM; k0 += 32) {
        int slot = ((k0 >> 3) + kg) ^ (r & 7);
        bf16x8 a = *(const bf16x8*)((const char*)hs + r * 512 + (slot << 4));
        bf16x8 b = *(const bf16x8*)(w2t + (size_t)(wn + r) * H_DIM + k0 + kg * 8);
        acc = __builtin_amdgcn_mfma_f32_16x16x32_bf16(a, b, acc, 0, 0, 0);
    }

#pragma unroll
    for (int i = 0; i < 4; ++i) {
        int row = nb + kg * 4 + i;
        float di = rsqrtf((float)cnt[row] + 1.0f);
        g2b[(size_t)row * O_DIM + wn + r] = f2bf(di * acc[i]);
    }
}

// ---------------- K4: fused gather layer 2 + head (ushort2 loads, 2-wave split) ----------------
__global__ __launch_bounds__(128) void gather_head_kernel(
    const unsigned short* __restrict__ g2,   // [8192][128] bf16, dinv-scaled
    const int* __restrict__ cnt, const int* __restrict__ slots,
    const float* __restrict__ b2,
    const float* __restrict__ Wmu, const float* __restrict__ bmu,
    const float* __restrict__ Wlv, const float* __restrict__ blv,
    const float* __restrict__ eps,
    float* __restrict__ mu_out, float* __restrict__ lv_out,
    _Float16* __restrict__ zr)
{
    __shared__ float zsw[2][O_DIM];
    __shared__ float zs[O_DIM];
    __shared__ float mu_s[C_DIM];
    __shared__ float lv_s[C_DIM];
    const int node = blockIdx.x;
    const int t = threadIdx.x;
    const int w = t >> 6;
    const int lane = t & 63;

    const int deg = cnt[node];
    const int* sl = slots + node * BCAP;
    const unsigned int* G2 = (const unsigned int*)g2;  // row stride 64 uints (128 bf16)

    float a0 = 0.f, a1 = 0.f, c0 = 0.f, c1 = 0.f;
    if (w == 0) {
        unsigned int u = G2[(size_t)node * 64 + lane];
        a0 = bf2f((unsigned short)u);
        a1 = bf2f((unsigned short)(u >> 16));
    }
    int e = w;
    for (; e + 6 < deg; e += 8) {
        unsigned int u0 = G2[(size_t)sl[e]     * 64 + lane];
        unsigned int u1 = G2[(size_t)sl[e + 2] * 64 + lane];
        unsigned int u2 = G2[(size_t)sl[e + 4] * 64 + lane];
        unsigned int u3 = G2[(size_t)sl[e + 6] * 64 + lane];
        a0 += bf2f((unsigned short)u0) + bf2f((unsigned short)u1);
        a1 += bf2f((unsigned short)(u0 >> 16)) + bf2f((unsigned short)(u1 >> 16));
        c0 += bf2f((unsigned short)u2) + bf2f((unsigned short)u3);
        c1 += bf2f((unsigned short)(u2 >> 16)) + bf2f((unsigned short)(u3 >> 16));
    }
    for (; e < deg; e += 2) {
        unsigned int u = G2[(size_t)sl[e] * 64 + lane];
        a0 += bf2f((unsigned short)u);
        a1 += bf2f((unsigned short)(u >> 16));
    }
    zsw[w][2 * lane]     = a0 + c0;
    zsw[w][2 * lane + 1] = a1 + c1;
    __syncthreads();

    float dv = rsqrtf((float)deg + 1.0f);
    zs[t] = dv * (zsw[0][t] + zsw[1][t]) + b2[t];
    __syncthreads();

    const int c = t & 63;
    const float* W = (t < 64) ? Wmu : Wlv;
    float s = 0.f;
#pragma unroll 8
    for (int k = 0; k < O_DIM; ++k) s += zs[k] * W[k * C_DIM + c];
    if (t < 64) {
        s += bmu[c];
        mu_out[(size_t)node * C_DIM + c] = s;
        mu_s[c] = s;
    } else {
        s += blv[c];
        lv_out[(size_t)node * C_DIM + c] = s;
        lv_s[c] = s;
    }
    __syncthreads();
    if (t < 64) {
        float stdv = __expf(0.5f * lv_s[c]);
        float v = mu_s[c] + eps[(size_t)node * C_DIM + c] * stdv;
        zr[(size_t)node * C_DIM + c] = (_Float16)v;
    }
}

// ---------------- K5: adj = sigmoid(zr @ zr^T), fp16 MFMA, LDS-staged coalesced NT stores ----------------
__global__ __launch_bounds__(256) void adj_mfma_kernel(
    const _Float16* __restrict__ Z, float* __restrict__ out)
{
    __shared__ float ls[128 * 128];   // 64 KB; float4-slot XOR-swizzled by row&7
    const int tid = threadIdx.x;
    const int lane = tid & 63;
    const int wid = tid >> 6;
    const int r = lane & 15;
    const int kg = lane >> 4;
    const int mb = blockIdx.y * 128;
    const int nb = blockIdx.x * 128;
    const int m0 = (wid >> 1) * 64;
    const int n0 = (wid & 1) * 64;

    f16x8 a[4][2], b[4][2];
#pragma unroll
    for (int mi = 0; mi < 4; ++mi)
#pragma unroll
        for (int ks = 0; ks < 2; ++ks) {
            a[mi][ks] = *(const f16x8*)(Z + (size_t)(mb + m0 + mi * 16 + r) * C_DIM + ks * 32 + kg * 8);
            b[mi][ks] = *(const f16x8*)(Z + (size_t)(nb + n0 + mi * 16 + r) * C_DIM + ks * 32 + kg * 8);
        }

    f32x4 acc[4][4];
#pragma unroll
    for (int mi = 0; mi < 4; ++mi)
#pragma unroll
        for (int ni = 0; ni < 4; ++ni) acc[mi][ni] = (f32x4){0.f, 0.f, 0.f, 0.f};

#pragma unroll
    for (int mi = 0; mi < 4; ++mi)
#pragma unroll
        for (int ni = 0; ni < 4; ++ni) {
            acc[mi][ni] = __builtin_amdgcn_mfma_f32_16x16x32_f16(a[mi][0], b[ni][0], acc[mi][ni], 0, 0, 0);
            acc[mi][ni] = __builtin_amdgcn_mfma_f32_16x16x32_f16(a[mi][1], b[ni][1], acc[mi][ni], 0, 0, 0);
        }

    // sigmoid -> LDS (swizzled float4 slots)
#pragma unroll
    for (int mi = 0; mi < 4; ++mi) {
        int lr_b = m0 + mi * 16 + kg * 4;
#pragma unroll
        for (int ni = 0; ni < 4; ++ni) {
            int lc = n0 + ni * 16 + r;
#pragma unroll
            for (int i = 0; i < 4; ++i) {
                float v = acc[mi][ni][i];
                float e = __expf(-v);
                float sg = __builtin_amdgcn_rcpf(1.0f + e);
                int lr = lr_b + i;
                ls[lr * 128 + (((lc >> 2) ^ (lr & 7)) << 2) + (lc & 3)] = sg;
            }
        }
    }
    __syncthreads();

    // coalesced NT stores: 512B contiguous per wave-instruction
#pragma unroll
    for (int j = 0; j < 16; ++j) {
        int idx = j * 256 + tid;
        int row = idx >> 5;
        int s = idx & 31;
        f32x4 v = *(const f32x4*)&ls[row * 128 + (((s ^ (row & 7)) & 31) << 2)];
        __builtin_nontemporal_store(v, (f32x4*)&out[(size_t)(mb + row) * N_NODES + nb + s * 4]);
    }
}

extern "C" void kernel_launch(void* const* d_in, const int* in_sizes, int n_in,
                              void* d_out, int out_size, void* d_ws, size_t ws_size,
                              hipStream_t stream) {
    const float* x   = (const float*)d_in[0];
    const int*   ei  = (const int*)  d_in[1];
    const float* eps = (const float*)d_in[2];
    const float* W1  = (const float*)d_in[3];
    const float* b1  = (const float*)d_in[4];
    const float* W2  = (const float*)d_in[5];
    const float* b2  = (const float*)d_in[6];
    const float* Wmu = (const float*)d_in[7];
    const float* bmu = (const float*)d_in[8];
    const float* Wlv = (const float*)d_in[9];
    const float* blv = (const float*)d_in[10];
    float* out = (float*)d_out;

    const int* srcv = ei;
    const int* dstv = ei + E_EDGES;

    char* p = (char*)d_ws;
    auto carve = [&](size_t bytes) -> void* {
        void* q = (void*)p;
        p += (bytes + 255) & ~(size_t)255;
        return q;
    };
    int* cnt      = (int*)carve(N_NODES * 4);
    int* slots    = (int*)carve((size_t)N_NODES * BCAP * 4);
    unsigned short* w1t  = (unsigned short*)carve((size_t)F_IN * H_DIM * 2);
    unsigned short* w2t  = (unsigned short*)carve((size_t)H_DIM * O_DIM * 2);
    unsigned short* raw1 = (unsigned short*)carve((size_t)N_NODES * H_DIM * 2);
    unsigned short* g2b  = (unsigned short*)carve((size_t)N_NODES * O_DIM * 2);
    _Float16* zr         = (_Float16*)carve((size_t)N_NODES * C_DIM * 2);

    float* mu_out = out + (size_t)N_NODES * N_NODES;
    float* lv_out = mu_out + (size_t)N_NODES * C_DIM;

    // ---- 1. prep: cnt zero + W1^T bf16 + W2^T bf16 ----
    {
        const int total = F_IN * H_DIM + H_DIM * O_DIM;  // 163840
        prep_kernel<<<(total + 255) / 256, 256, 0, stream>>>(
            W1, w1t, W2, w2t, cnt);
    }

    // ---- 2. gemm1: edge bucket-fill + raw1 = bf16(x)@w1t^T, 64x64 tiles, 512 blocks ----
    {
        dim3 grid(H_DIM / 64, N_NODES / 64);   // 4 x 128 = 512 blocks
        gemm1_kernel<<<grid, 256, 0, stream>>>(
            x, w1t, srcv, dstv, cnt, slots, raw1);
    }

    // ---- 3. fused gather1 + gemm2 -> g2b ----
    gather_gemm2_kernel<<<N_NODES / 16, 512, 0, stream>>>(
        raw1, cnt, slots, b1, w2t, g2b);

    // ---- 4. fused gather 2 + head (zr fp16) ----
    gather_head_kernel<<<N_NODES, 128, 0, stream>>>(
        g2b, cnt, slots, b2, Wmu, bmu, Wlv, blv, eps,
        mu_out, lv_out, zr);

    // ---- 5. adjacency reconstruction (LDS-staged coalesced NT stores) ----
    {
        dim3 grid(N_NODES / 128, N_NODES / 128);
        adj_mfma_kernel<<<grid, 256, 0, stream>>>(zr, out);
    }
}